// Round 8
// baseline (307.402 us; speedup 1.0000x reference)
//
#include <hip/hip_runtime.h>

// CrossAttention B=8, N1=N2=2048, D=512 — all-fp16 MFMA pipeline, R12.
//  prep : in1 -> x16,xt ; in2 -> k16,vt   (LDS-tiled transpose, coalesced writes)
//  q    = in1 @ W^T + b   (fp16 MFMA, BK=64, 32KB drain @4/CU) -> q16
//  S    = q @ in2^T       (fp16 MFMA, 32KB drain @4/CU)        -> fp16, 64 MiB
//  stats= per-row {max, 1/sum} only (128 KB)  — replaces materialized softmax
//  out  = merged out1/out2, 128x256 BK=64 drain; exp(S-m)*inv applied in the
//         operand path (bit-identical to old P), P buffer eliminated.
// R11 post-mortem: out12 at the 2-barrier-drain ceiling (~880 TF, Mfma 35%);
// remaining pot is the unprofiled ~190us. R12 removes k_softmax's 128MB
// round-trip (~27us) for a 13us stats kernel + VALU fused into out12's slack.

typedef _Float16 f16x8 __attribute__((ext_vector_type(8)));
typedef _Float16 f16x4 __attribute__((ext_vector_type(4)));
typedef float floatx4 __attribute__((ext_vector_type(4)));
typedef __attribute__((address_space(1))) const void* gptr_t;
typedef __attribute__((address_space(3))) void* lptr_t;

union F8 { f16x8 v; _Float16 h[8]; unsigned short u[8]; unsigned w[4]; };
union F4 { f16x4 v; _Float16 h[4]; unsigned u2[2]; };
union HS { unsigned short s; _Float16 h; };

__device__ __forceinline__ void gld16(const void* g, void* l) {
    __builtin_amdgcn_global_load_lds((gptr_t)g, (lptr_t)l, 16, 0, 0);
}
__device__ __forceinline__ floatx4 mfma16(f16x8 a, f16x8 b, floatx4 c) {
    return __builtin_amdgcn_mfma_f32_16x16x32_f16(a, b, c, 0, 0, 0);
}

// ---- BK=64 tiles: XOR swizzle over 8 octs (oct ^= row&7) --------------------
template <int ROWS>
__device__ __forceinline__ void stage64(const _Float16* g, int ldg,
                                        _Float16* lds, int tid) {
#pragma unroll
    for (int c = 0; c < (ROWS * 8) / 256; ++c) {
        const int q = c * 256 + tid;
        const int row = q >> 3;
        const int oct = (q & 7) ^ (row & 7);
        gld16(g + (size_t)row * ldg + oct * 8, lds + q * 8);
    }
}
__device__ __forceinline__ f16x8 ldfrag64(const _Float16* lds, int row, int j) {
    return *(const f16x8*)&lds[row * 64 + ((j ^ (row & 7)) << 3)];
}
// out2's transposed-A tile: writes have even rows only, so swizzle on (row>>1)
// to cover all 8 oct values (all 32 banks) per wave-write.
__device__ __forceinline__ f16x8 ldfragA(const _Float16* lds, int row, int j) {
    return *(const f16x8*)&lds[row * 64 + ((j ^ ((row >> 1) & 7)) << 3)];
}

// ---------------- prep: fp32 [b][n][512] -> row fp16 + col fp16 --------------
#define TS 66
__global__ __launch_bounds__(256) void k_prep2(
    const float* __restrict__ in1, const float* __restrict__ in2,
    _Float16* __restrict__ x16, _Float16* __restrict__ xt,
    _Float16* __restrict__ k16, _Float16* __restrict__ vt)
{
    __shared__ __align__(16) _Float16 T[64 * TS];
    const int z = blockIdx.z;
    const int b = z & 7;
    const float* src = (z < 8 ? in1 : in2);
    _Float16* rowo = (z < 8 ? x16 : k16);
    _Float16* colo = (z < 8 ? xt : vt);
    const int d0 = blockIdx.x * 64, n0 = blockIdx.y * 64;
    const float* Sp = src + (size_t)b * 2048 * 512;
    _Float16* Rp = rowo + (size_t)b * 2048 * 512;
    _Float16* Cp = colo + (size_t)b * 512 * 2048;
    const int t = threadIdx.x;

#pragma unroll
    for (int c = 0; c < 4; c++) {
        const int q = c * 256 + t, r = q >> 4, c4 = q & 15;
        const float4 g = *(const float4*)(Sp + (size_t)(n0 + r) * 512 + d0 + c4 * 4);
        F4 w;
        w.h[0] = (_Float16)g.x; w.h[1] = (_Float16)g.y;
        w.h[2] = (_Float16)g.z; w.h[3] = (_Float16)g.w;
        *(f16x4*)(Rp + (size_t)(n0 + r) * 512 + d0 + c4 * 4) = w.v;
        *(unsigned*)&T[r * TS + c4 * 4]     = w.u2[0];
        *(unsigned*)&T[r * TS + c4 * 4 + 2] = w.u2[1];
    }
    __syncthreads();
    const int c8 = t & 7, drp = (t >> 3) * 2;
    F8 w0, w1;
#pragma unroll
    for (int i = 0; i < 8; i++) {
        const unsigned g = *(const unsigned*)&T[(c8 * 8 + i) * TS + drp];
        w0.u[i] = (unsigned short)(g & 0xffffu);
        w1.u[i] = (unsigned short)(g >> 16);
    }
    *(f16x8*)(Cp + (size_t)(d0 + drp) * 2048 + n0 + c8 * 8) = w0.v;
    *(f16x8*)(Cp + (size_t)(d0 + drp + 1) * 2048 + n0 + c8 * 8) = w1.v;
}

// ---------------- prep: fp32 -> fp16 elementwise (for W) ---------------------
__global__ __launch_bounds__(256) void k_cvt(const float* __restrict__ src,
                                             _Float16* __restrict__ dst)
{
    const size_t i = ((size_t)blockIdx.x * 256 + threadIdx.x) * 8;
    float4 a = *(const float4*)(src + i);
    float4 b = *(const float4*)(src + i + 4);
    F8 w;
    w.h[0] = (_Float16)a.x; w.h[1] = (_Float16)a.y;
    w.h[2] = (_Float16)a.z; w.h[3] = (_Float16)a.w;
    w.h[4] = (_Float16)b.x; w.h[5] = (_Float16)b.y;
    w.h[6] = (_Float16)b.z; w.h[7] = (_Float16)b.w;
    *(f16x8*)(dst + i) = w.v;
}

// ---------------- K1: q = in1 @ W^T + bias (128x128, BK=64) ------------------
__global__ __launch_bounds__(256, 4) void k_qgemm16(
    const _Float16* __restrict__ A, const _Float16* __restrict__ W,
    const float* __restrict__ bias, _Float16* __restrict__ q)
{
    __shared__ __align__(16) _Float16 As[128 * 64], Bs[128 * 64];
    const int tid = threadIdx.x;
    const int lane = tid & 63, wave = tid >> 6;
    const int wM = (wave >> 1) * 64, wN = (wave & 1) * 64;
    const int lrow = lane & 15, kq = lane >> 4;
    const int bi = blockIdx.x;
    const int r0 = (bi >> 2) * 128, c0 = (bi & 3) * 128;

    floatx4 acc[4][4];
#pragma unroll
    for (int i = 0; i < 4; i++)
#pragma unroll
        for (int j = 0; j < 4; j++) acc[i][j] = (floatx4){0.f, 0.f, 0.f, 0.f};

    for (int k0 = 0; k0 < 512; k0 += 64) {
        stage64<128>(A + (size_t)r0 * 512 + k0, 512, As, tid);
        stage64<128>(W + (size_t)c0 * 512 + k0, 512, Bs, tid);
        __syncthreads();
#pragma unroll
        for (int ks = 0; ks < 2; ks++) {
            f16x8 a[4], b[4];
#pragma unroll
            for (int i = 0; i < 4; i++) {
                a[i] = ldfrag64(As, wM + i * 16 + lrow, ks * 4 + kq);
                b[i] = ldfrag64(Bs, wN + i * 16 + lrow, ks * 4 + kq);
            }
#pragma unroll
            for (int mi = 0; mi < 4; mi++)
#pragma unroll
                for (int ni = 0; ni < 4; ni++)
                    acc[mi][ni] = mfma16(a[mi], b[ni], acc[mi][ni]);
        }
        __syncthreads();
    }
#pragma unroll
    for (int ni = 0; ni < 4; ni++) {
        const int col = c0 + wN + ni * 16 + lrow;
        const float bv = bias[col];
#pragma unroll
        for (int mi = 0; mi < 4; mi++) {
            const int row = r0 + wM + mi * 16 + kq * 4;
#pragma unroll
            for (int r = 0; r < 4; r++)
                q[(size_t)(row + r) * 512 + col] = (_Float16)(acc[mi][ni][r] + bv);
        }
    }
}

// ---------------- K2: S = q @ in2^T -> fp16 logits (full batch) --------------
__global__ __launch_bounds__(256, 4) void k_scores16(
    const _Float16* __restrict__ q, const _Float16* __restrict__ k,
    _Float16* __restrict__ S)
{
    __shared__ __align__(16) _Float16 As[128 * 64], Bs[128 * 64];
    const int tid = threadIdx.x;
    const int lane = tid & 63, wave = tid >> 6;
    const int wM = (wave >> 1) * 64, wN = (wave & 1) * 64;
    const int lrow = lane & 15, kq = lane >> 4;
    const int bi = blockIdx.x;
    const int bz = bi & 7, t = bi >> 3;       // low bits = batch -> L3 coherence
    const int c0 = (t & 15) * 128, r0 = (t >> 4) * 128;
    const _Float16* qp = q + (size_t)bz * 2048 * 512;
    const _Float16* kp = k + (size_t)bz * 2048 * 512;
    _Float16* Sp = S + (size_t)bz * 2048 * 2048;

    floatx4 acc[4][4];
#pragma unroll
    for (int i = 0; i < 4; i++)
#pragma unroll
        for (int j = 0; j < 4; j++) acc[i][j] = (floatx4){0.f, 0.f, 0.f, 0.f};

    for (int k0 = 0; k0 < 512; k0 += 64) {
        stage64<128>(qp + (size_t)r0 * 512 + k0, 512, As, tid);
        stage64<128>(kp + (size_t)c0 * 512 + k0, 512, Bs, tid);
        __syncthreads();
#pragma unroll
        for (int ks = 0; ks < 2; ks++) {
            f16x8 a[4], b[4];
#pragma unroll
            for (int i = 0; i < 4; i++) {
                a[i] = ldfrag64(As, wM + i * 16 + lrow, ks * 4 + kq);
                b[i] = ldfrag64(Bs, wN + i * 16 + lrow, ks * 4 + kq);
            }
#pragma unroll
            for (int mi = 0; mi < 4; mi++)
#pragma unroll
                for (int ni = 0; ni < 4; ni++)
                    acc[mi][ni] = mfma16(a[mi], b[ni], acc[mi][ni]);
        }
        __syncthreads();
    }
#pragma unroll
    for (int mi = 0; mi < 4; mi++)
#pragma unroll
        for (int ni = 0; ni < 4; ni++) {
            const int row = r0 + wM + mi * 16 + kq * 4;
            const int col = c0 + wN + ni * 16 + lrow;
            _Float16* dst = Sp + (size_t)row * 2048 + col;
#pragma unroll
            for (int r = 0; r < 4; r++) dst[(size_t)r * 2048] = (_Float16)acc[mi][ni][r];
        }
}

// ---------------- K3: row stats {m, 1/sum} — same reduction order as the old
// softmax so downstream exp(v-m)*inv is BIT-IDENTICAL to the old P. ----------
__global__ __launch_bounds__(256) void k_stats(const _Float16* __restrict__ S,
                                               float2* __restrict__ st)
{
    const int wave = threadIdx.x >> 6, lane = threadIdx.x & 63;
    const int row = blockIdx.x * 4 + wave;
    const _Float16* s = S + (size_t)row * 2048;

    F8 raw[4];
    float v[32];
#pragma unroll
    for (int c = 0; c < 4; c++) {
        raw[c].v = *(const f16x8*)(s + c * 512 + lane * 8);
#pragma unroll
        for (int i = 0; i < 8; i++) v[c * 8 + i] = (float)raw[c].h[i];
    }
    float m = v[0];
#pragma unroll
    for (int i = 1; i < 32; i++) m = fmaxf(m, v[i]);
#pragma unroll
    for (int off = 32; off >= 1; off >>= 1) m = fmaxf(m, __shfl_xor(m, off));

    float sum = 0.f;
#pragma unroll
    for (int i = 0; i < 32; i++) { v[i] = __expf(v[i] - m); sum += v[i]; }
#pragma unroll
    for (int off = 32; off >= 1; off >>= 1) sum += __shfl_xor(sum, off);
    const float inv = 1.0f / sum;

    if (lane == 0) st[row] = make_float2(m, inv);
}

// ---------------- K4: merged out1/out2, 128x256 x BK=64, fused exp -----------
// even blocks: out1 = P @ Vt   (A = exp(S-m)*inv applied after ldfrag)
// odd  blocks: out2 = P^T @ Xt (A = exp applied during reg transpose)
__device__ __forceinline__ void loadtr16(const _Float16* Pp, int r0, int mPair,
                                         int kBase, int k0, unsigned (&u)[16]) {
#pragma unroll
    for (int j = 0; j < 16; j++)
        u[j] = *(const unsigned*)(
            Pp + (size_t)(k0 + kBase + j) * 2048 + r0 + mPair);
}

__global__ __launch_bounds__(256, 2) void k_out12(
    const _Float16* __restrict__ S, const float2* __restrict__ st,
    const _Float16* __restrict__ Vt, const _Float16* __restrict__ Xt,
    float* __restrict__ O1, float* __restrict__ O2)
{
    __shared__ __align__(16) _Float16 lds[24576];   // 48 KiB: A @0, B @8192
    const int tid = threadIdx.x;
    const int lane = tid & 63, wave = tid >> 6;
    const int wM = (wave >> 1) * 64, wN = (wave & 1) * 128;
    const int lrow = lane & 15, kq = lane >> 4;
    const bool isO2 = blockIdx.x & 1;               // interleave -> co-residency
    const int bi = blockIdx.x >> 1;
    const int bz = bi & 7, t = bi >> 3;             // low bits = batch -> L3
    const int c0 = (t & 1) * 256, r0 = (t >> 1) * 128;
    const _Float16* Sp = S + (size_t)bz * 2048 * 2048;
    const float2* sp = st + (size_t)bz * 2048;
    const _Float16* Bp = (isO2 ? Xt : Vt) + (size_t)bz * 512 * 2048;
    float* Op = (isO2 ? O2 : O1) + (size_t)bz * 2048 * 512;

    floatx4 acc[4][8];
#pragma unroll
    for (int i = 0; i < 4; i++)
#pragma unroll
        for (int j = 0; j < 8; j++) acc[i][j] = (floatx4){0.f, 0.f, 0.f, 0.f};

    if (!isO2) {
        // per-lane A-fragment rows are fixed: preload their {m, inv}
        float am[4], ai[4];
#pragma unroll
        for (int i = 0; i < 4; i++) {
            const float2 s2 = sp[r0 + wM + i * 16 + lrow];
            am[i] = s2.x; ai[i] = s2.y;
        }
        for (int k0 = 0; k0 < 2048; k0 += 64) {
            stage64<128>(Sp + (size_t)r0 * 2048 + k0, 2048, lds, tid);
            stage64<256>(Bp + (size_t)c0 * 2048 + k0, 2048, lds + 8192, tid);
            __syncthreads();
#pragma unroll
            for (int ks = 0; ks < 2; ks++) {
                f16x8 a[4], b[8];
#pragma unroll
                for (int i = 0; i < 4; i++) {
                    F8 ra, pa;
                    ra.v = ldfrag64(lds, wM + i * 16 + lrow, ks * 4 + kq);
#pragma unroll
                    for (int j = 0; j < 8; j++)
                        pa.h[j] = (_Float16)(__expf((float)ra.h[j] - am[i]) * ai[i]);
                    a[i] = pa.v;
                }
#pragma unroll
                for (int i = 0; i < 8; i++)
                    b[i] = ldfrag64(lds + 8192, wN + i * 16 + lrow, ks * 4 + kq);
#pragma unroll
                for (int mi = 0; mi < 4; mi++)
#pragma unroll
                    for (int ni = 0; ni < 8; ni++)
                        acc[mi][ni] = mfma16(a[mi], b[ni], acc[mi][ni]);
            }
            __syncthreads();   // compute done before next restage (WAR)
        }
    } else {
        _Float16* As_ = lds;                // 128 x 64, transposed P
        const int mPair = (tid & 63) * 2;   // m pair within 128-tile
        const int kBase = (tid >> 6) * 16;  // 16 k's per thread

        unsigned u[16];
        loadtr16(Sp, r0, mPair, kBase, 0, u);
        for (int k0 = 0; k0 < 2048; k0 += 64) {
            // transpose S[k][m] -> As[m][k] applying exp(v-m[k])*inv[k];
            // (row>>1)&7 swizzle: even rows cover all 8 oct groups.
            const int sw = (mPair >> 1) & 7;
#pragma unroll
            for (int half = 0; half < 2; half++) {
                const int oct = (kBase >> 3) + half;
                F8 w0, w1;
#pragma unroll
                for (int j = 0; j < 8; j++) {
                    const unsigned g = u[half * 8 + j];
                    const float2 s2 = sp[k0 + kBase + half * 8 + j];  // uniform
                    HS lo, hi;
                    lo.s = (unsigned short)(g & 0xffffu);
                    hi.s = (unsigned short)(g >> 16);
                    w0.h[j] = (_Float16)(__expf((float)lo.h - s2.x) * s2.y);
                    w1.h[j] = (_Float16)(__expf((float)hi.h - s2.x) * s2.y);
                }
                *(f16x8*)&As_[mPair * 64 + ((oct ^ sw) << 3)] = w0.v;
                *(f16x8*)&As_[(mPair + 1) * 64 + ((oct ^ sw) << 3)] = w1.v;
            }
            stage64<256>(Bp + (size_t)c0 * 2048 + k0, 2048, lds + 8192, tid);
            __syncthreads();   // drains B gld16; As ds_writes visible
            if (k0 < 2048 - 64)
                loadtr16(Sp, r0, mPair, kBase, k0 + 64, u);   // fly under MFMA
#pragma unroll
            for (int ks = 0; ks < 2; ks++) {
                f16x8 a[4], b[8];
#pragma unroll
                for (int i = 0; i < 4; i++)
                    a[i] = ldfragA(As_, wM + i * 16 + lrow, ks * 4 + kq);
#pragma unroll
                for (int i = 0; i < 8; i++)
                    b[i] = ldfrag64(lds + 8192, wN + i * 16 + lrow, ks * 4 + kq);
#pragma unroll
                for (int mi = 0; mi < 4; mi++)
#pragma unroll
                    for (int ni = 0; ni < 8; ni++)
                        acc[mi][ni] = mfma16(a[mi], b[ni], acc[mi][ni]);
            }
            __syncthreads();   // WAR: next iter rewrites As/Bs
        }
    }
#pragma unroll
    for (int mi = 0; mi < 4; mi++)
#pragma unroll
        for (int ni = 0; ni < 8; ni++) {
            const int row = r0 + wM + mi * 16 + kq * 4;
            const int col = c0 + wN + ni * 16 + lrow;
            float* dst = Op + (size_t)row * 512 + col;
#pragma unroll
            for (int r = 0; r < 4; r++) dst[(size_t)r * 512] = acc[mi][ni][r];
        }
}

extern "C" void kernel_launch(void* const* d_in, const int* in_sizes, int n_in,
                              void* d_out, int out_size, void* d_ws, size_t ws_size,
                              hipStream_t stream)
{
    (void)in_sizes; (void)n_in; (void)out_size; (void)ws_size;
    const float* in1 = (const float*)d_in[0];
    const float* in2 = (const float*)d_in[1];
    const float* Ww  = (const float*)d_in[2];
    const float* Wb  = (const float*)d_in[3];
    float* out = (float*)d_out;

    char* ws = (char*)d_ws;
    _Float16* S   = (_Float16*)ws;                       // 64 MiB (fp16, full batch)
    float2*   st  = (float2*)(ws + 67108864ull);         // 128 KiB row stats
    _Float16* q16 = (_Float16*)(ws + 134217728ull);      // 16 MiB
    _Float16* x16 = (_Float16*)(ws + 150994944ull);      // 16 MiB
    _Float16* k16 = (_Float16*)(ws + 167772160ull);      // 16 MiB
    _Float16* vt  = (_Float16*)(ws + 184549376ull);      // 16 MiB
    _Float16* xt  = (_Float16*)(ws + 201326592ull);      // 16 MiB
    _Float16* w16 = (_Float16*)(ws + 218103808ull);      // 0.5 MiB

    k_prep2<<<dim3(8, 32, 16), 256, 0, stream>>>(in1, in2, x16, xt, k16, vt);
    k_cvt <<<128, 256, 0, stream>>>(Ww, w16);
    k_qgemm16<<<512, 256, 0, stream>>>(x16, w16, Wb, q16);
    k_scores16<<<2048, 256, 0, stream>>>(q16, k16, S);
    k_stats<<<4096, 256, 0, stream>>>(S, st);
    k_out12<<<512, 256, 0, stream>>>(S, st, vt, xt, out, out + 8388608);
}

// Round 9
// 256.380 us; speedup vs baseline: 1.1990x; 1.1990x over previous
//
#include <hip/hip_runtime.h>

// CrossAttention B=8, N1=N2=2048, D=512 — all-fp16 MFMA pipeline, R13.
//  prep : in1 -> x16,xt ; in2 -> k16,vt ; W -> w16 (z==16 branch, cvt folded)
//  q    = in1 @ W^T + b   (fp16 MFMA, BK=64, 32KB drain @4/CU) -> q16
//  S    = q @ in2^T       (fp16 MFMA, 128x256 BK=64 drain @2/CU) -> fp16, 64 MiB
//  P    = softmax(S)      wave-per-row, no LDS/barriers (materialized — R12
//         showed exp fused into the MFMA operand path costs 2x its save)
//  out  = merged out1/out2, 128x256 BK=64 drain (R11 structure, ~890 TF)
// R12 post-mortem: exp-in-operand-path put ~500cy VALU/trans per 307cy of MFMA
// on the critical path (VALU 40%, Mfma 23, +40us). Reverted. R13 single lever:
// scores16 gets the R11-proven 128x256 widening (64 MFMA/wave per drain).

typedef _Float16 f16x8 __attribute__((ext_vector_type(8)));
typedef _Float16 f16x4 __attribute__((ext_vector_type(4)));
typedef float floatx4 __attribute__((ext_vector_type(4)));
typedef __attribute__((address_space(1))) const void* gptr_t;
typedef __attribute__((address_space(3))) void* lptr_t;

union F8 { f16x8 v; _Float16 h[8]; unsigned short u[8]; unsigned w[4]; };
union F4 { f16x4 v; _Float16 h[4]; unsigned u2[2]; };

__device__ __forceinline__ void gld16(const void* g, void* l) {
    __builtin_amdgcn_global_load_lds((gptr_t)g, (lptr_t)l, 16, 0, 0);
}
__device__ __forceinline__ floatx4 mfma16(f16x8 a, f16x8 b, floatx4 c) {
    return __builtin_amdgcn_mfma_f32_16x16x32_f16(a, b, c, 0, 0, 0);
}

// ---- BK=64 tiles: XOR swizzle over 8 octs (oct ^= row&7) --------------------
template <int ROWS>
__device__ __forceinline__ void stage64(const _Float16* g, int ldg,
                                        _Float16* lds, int tid) {
#pragma unroll
    for (int c = 0; c < (ROWS * 8) / 256; ++c) {
        const int q = c * 256 + tid;
        const int row = q >> 3;
        const int oct = (q & 7) ^ (row & 7);
        gld16(g + (size_t)row * ldg + oct * 8, lds + q * 8);
    }
}
__device__ __forceinline__ f16x8 ldfrag64(const _Float16* lds, int row, int j) {
    return *(const f16x8*)&lds[row * 64 + ((j ^ (row & 7)) << 3)];
}
// out2's transposed-A tile: writes have even rows only, so swizzle on (row>>1)
// to cover all 8 oct values (all 32 banks) per wave-write.
__device__ __forceinline__ f16x8 ldfragA(const _Float16* lds, int row, int j) {
    return *(const f16x8*)&lds[row * 64 + ((j ^ ((row >> 1) & 7)) << 3)];
}

// ---------------- prep: fp32 [b][n][512] -> row fp16 + col fp16; W cvt -------
#define TS 66
__global__ __launch_bounds__(256) void k_prep2(
    const float* __restrict__ in1, const float* __restrict__ in2,
    _Float16* __restrict__ x16, _Float16* __restrict__ xt,
    _Float16* __restrict__ k16, _Float16* __restrict__ vt,
    const float* __restrict__ Ww, _Float16* __restrict__ w16)
{
    __shared__ __align__(16) _Float16 T[64 * TS];
    const int z = blockIdx.z;
    const int t = threadIdx.x;
    if (z == 16) {   // folded W conversion: 512x512 fp32 -> fp16 (128 blocks)
        const int flat = blockIdx.y * 8 + blockIdx.x;
        if (flat < 128) {
            const size_t i = ((size_t)flat * 256 + t) * 8;
            float4 a = *(const float4*)(Ww + i);
            float4 b = *(const float4*)(Ww + i + 4);
            F8 w;
            w.h[0] = (_Float16)a.x; w.h[1] = (_Float16)a.y;
            w.h[2] = (_Float16)a.z; w.h[3] = (_Float16)a.w;
            w.h[4] = (_Float16)b.x; w.h[5] = (_Float16)b.y;
            w.h[6] = (_Float16)b.z; w.h[7] = (_Float16)b.w;
            *(f16x8*)(w16 + i) = w.v;
        }
        return;
    }
    const int b = z & 7;
    const float* src = (z < 8 ? in1 : in2);
    _Float16* rowo = (z < 8 ? x16 : k16);
    _Float16* colo = (z < 8 ? xt : vt);
    const int d0 = blockIdx.x * 64, n0 = blockIdx.y * 64;
    const float* Sp = src + (size_t)b * 2048 * 512;
    _Float16* Rp = rowo + (size_t)b * 2048 * 512;
    _Float16* Cp = colo + (size_t)b * 512 * 2048;

#pragma unroll
    for (int c = 0; c < 4; c++) {
        const int q = c * 256 + t, r = q >> 4, c4 = q & 15;
        const float4 g = *(const float4*)(Sp + (size_t)(n0 + r) * 512 + d0 + c4 * 4);
        F4 w;
        w.h[0] = (_Float16)g.x; w.h[1] = (_Float16)g.y;
        w.h[2] = (_Float16)g.z; w.h[3] = (_Float16)g.w;
        *(f16x4*)(Rp + (size_t)(n0 + r) * 512 + d0 + c4 * 4) = w.v;
        *(unsigned*)&T[r * TS + c4 * 4]     = w.u2[0];
        *(unsigned*)&T[r * TS + c4 * 4 + 2] = w.u2[1];
    }
    __syncthreads();
    const int c8 = t & 7, drp = (t >> 3) * 2;
    F8 w0, w1;
#pragma unroll
    for (int i = 0; i < 8; i++) {
        const unsigned g = *(const unsigned*)&T[(c8 * 8 + i) * TS + drp];
        w0.u[i] = (unsigned short)(g & 0xffffu);
        w1.u[i] = (unsigned short)(g >> 16);
    }
    *(f16x8*)(Cp + (size_t)(d0 + drp) * 2048 + n0 + c8 * 8) = w0.v;
    *(f16x8*)(Cp + (size_t)(d0 + drp + 1) * 2048 + n0 + c8 * 8) = w1.v;
}

// ---------------- K1: q = in1 @ W^T + bias (128x128, BK=64) ------------------
__global__ __launch_bounds__(256, 4) void k_qgemm16(
    const _Float16* __restrict__ A, const _Float16* __restrict__ W,
    const float* __restrict__ bias, _Float16* __restrict__ q)
{
    __shared__ __align__(16) _Float16 As[128 * 64], Bs[128 * 64];
    const int tid = threadIdx.x;
    const int lane = tid & 63, wave = tid >> 6;
    const int wM = (wave >> 1) * 64, wN = (wave & 1) * 64;
    const int lrow = lane & 15, kq = lane >> 4;
    const int bi = blockIdx.x;
    const int r0 = (bi >> 2) * 128, c0 = (bi & 3) * 128;

    floatx4 acc[4][4];
#pragma unroll
    for (int i = 0; i < 4; i++)
#pragma unroll
        for (int j = 0; j < 4; j++) acc[i][j] = (floatx4){0.f, 0.f, 0.f, 0.f};

    for (int k0 = 0; k0 < 512; k0 += 64) {
        stage64<128>(A + (size_t)r0 * 512 + k0, 512, As, tid);
        stage64<128>(W + (size_t)c0 * 512 + k0, 512, Bs, tid);
        __syncthreads();
#pragma unroll
        for (int ks = 0; ks < 2; ks++) {
            f16x8 a[4], b[4];
#pragma unroll
            for (int i = 0; i < 4; i++) {
                a[i] = ldfrag64(As, wM + i * 16 + lrow, ks * 4 + kq);
                b[i] = ldfrag64(Bs, wN + i * 16 + lrow, ks * 4 + kq);
            }
#pragma unroll
            for (int mi = 0; mi < 4; mi++)
#pragma unroll
                for (int ni = 0; ni < 4; ni++)
                    acc[mi][ni] = mfma16(a[mi], b[ni], acc[mi][ni]);
        }
        __syncthreads();
    }
#pragma unroll
    for (int ni = 0; ni < 4; ni++) {
        const int col = c0 + wN + ni * 16 + lrow;
        const float bv = bias[col];
#pragma unroll
        for (int mi = 0; mi < 4; mi++) {
            const int row = r0 + wM + mi * 16 + kq * 4;
#pragma unroll
            for (int r = 0; r < 4; r++)
                q[(size_t)(row + r) * 512 + col] = (_Float16)(acc[mi][ni][r] + bv);
        }
    }
}

// ---------------- K2: S = q @ in2^T (128x256, BK=64 drain, @2/CU) ------------
__global__ __launch_bounds__(256, 2) void k_scores16(
    const _Float16* __restrict__ q, const _Float16* __restrict__ k,
    _Float16* __restrict__ S)
{
    __shared__ __align__(16) _Float16 lds[24576];   // 48 KiB: A @0, B @8192
    const int tid = threadIdx.x;
    const int lane = tid & 63, wave = tid >> 6;
    const int wM = (wave >> 1) * 64, wN = (wave & 1) * 128;
    const int lrow = lane & 15, kq = lane >> 4;
    const int bi = blockIdx.x;
    const int bz = bi & 7, t = bi >> 3;       // low bits = batch -> L3 coherence
    const int c0 = (t & 7) * 256, r0 = (t >> 3) * 128;
    const _Float16* qp = q + (size_t)bz * 2048 * 512;
    const _Float16* kp = k + (size_t)bz * 2048 * 512;
    _Float16* Sp = S + (size_t)bz * 2048 * 2048;

    floatx4 acc[4][8];
#pragma unroll
    for (int i = 0; i < 4; i++)
#pragma unroll
        for (int j = 0; j < 8; j++) acc[i][j] = (floatx4){0.f, 0.f, 0.f, 0.f};

    for (int k0 = 0; k0 < 512; k0 += 64) {
        stage64<128>(qp + (size_t)r0 * 512 + k0, 512, lds, tid);
        stage64<256>(kp + (size_t)c0 * 512 + k0, 512, lds + 8192, tid);
        __syncthreads();
#pragma unroll
        for (int ks = 0; ks < 2; ks++) {
            f16x8 a[4], b[8];
#pragma unroll
            for (int i = 0; i < 4; i++)
                a[i] = ldfrag64(lds, wM + i * 16 + lrow, ks * 4 + kq);
#pragma unroll
            for (int i = 0; i < 8; i++)
                b[i] = ldfrag64(lds + 8192, wN + i * 16 + lrow, ks * 4 + kq);
#pragma unroll
            for (int mi = 0; mi < 4; mi++)
#pragma unroll
                for (int ni = 0; ni < 8; ni++)
                    acc[mi][ni] = mfma16(a[mi], b[ni], acc[mi][ni]);
        }
        __syncthreads();
    }
#pragma unroll
    for (int mi = 0; mi < 4; mi++)
#pragma unroll
        for (int ni = 0; ni < 8; ni++) {
            const int row = r0 + wM + mi * 16 + kq * 4;
            const int col = c0 + wN + ni * 16 + lrow;
            _Float16* dst = Sp + (size_t)row * 2048 + col;
#pragma unroll
            for (int r = 0; r < 4; r++) dst[(size_t)r * 2048] = (_Float16)acc[mi][ni][r];
        }
}

// ---------------- K3: row softmax, wave-per-row (no LDS, no barriers) --------
__global__ __launch_bounds__(256) void k_softmax(const _Float16* __restrict__ S,
                                                 _Float16* __restrict__ P)
{
    const int wave = threadIdx.x >> 6, lane = threadIdx.x & 63;
    const int row = blockIdx.x * 4 + wave;
    const _Float16* s = S + (size_t)row * 2048;
    _Float16* p = P + (size_t)row * 2048;

    F8 raw[4];
    float v[32];
#pragma unroll
    for (int c = 0; c < 4; c++) {
        raw[c].v = *(const f16x8*)(s + c * 512 + lane * 8);
#pragma unroll
        for (int i = 0; i < 8; i++) v[c * 8 + i] = (float)raw[c].h[i];
    }
    float m = v[0];
#pragma unroll
    for (int i = 1; i < 32; i++) m = fmaxf(m, v[i]);
#pragma unroll
    for (int off = 32; off >= 1; off >>= 1) m = fmaxf(m, __shfl_xor(m, off));

    float sum = 0.f;
#pragma unroll
    for (int i = 0; i < 32; i++) { v[i] = __expf(v[i] - m); sum += v[i]; }
#pragma unroll
    for (int off = 32; off >= 1; off >>= 1) sum += __shfl_xor(sum, off);
    const float inv = 1.0f / sum;

#pragma unroll
    for (int c = 0; c < 4; c++) {
        F8 w;
#pragma unroll
        for (int i = 0; i < 8; i++) w.h[i] = (_Float16)(v[c * 8 + i] * inv);
        *(f16x8*)(p + c * 512 + lane * 8) = w.v;
    }
}

// ---------------- K4: merged out1/out2, 128x256 x BK=64, DRAIN @2/CU ---------
// even blocks: out1 = P @ Vt      (A = P rows staged via gld16)
// odd  blocks: out2 = P^T @ Xt    (A = P reg-transposed into As)
// 48 KiB LDS (A 16K @0, B 32K @8192h); 64 MFMA/wave per drain;
// 512 blocks = 2/CU, one out1 + one out2 co-resident per CU.
__device__ __forceinline__ void loadtr16(const _Float16* Pp, int r0, int mPair,
                                         int kBase, int k0, unsigned (&u)[16]) {
#pragma unroll
    for (int j = 0; j < 16; j++)
        u[j] = *(const unsigned*)(
            Pp + (size_t)(k0 + kBase + j) * 2048 + r0 + mPair);
}

__global__ __launch_bounds__(256, 2) void k_out12(
    const _Float16* __restrict__ P, const _Float16* __restrict__ Vt,
    const _Float16* __restrict__ Xt, float* __restrict__ O1,
    float* __restrict__ O2)
{
    __shared__ __align__(16) _Float16 lds[24576];   // 48 KiB: A @0, B @8192
    const int tid = threadIdx.x;
    const int lane = tid & 63, wave = tid >> 6;
    const int wM = (wave >> 1) * 64, wN = (wave & 1) * 128;
    const int lrow = lane & 15, kq = lane >> 4;
    const bool isO2 = blockIdx.x & 1;               // interleave -> co-residency
    const int bi = blockIdx.x >> 1;
    const int bz = bi & 7, t = bi >> 3;             // low bits = batch -> L3
    const int c0 = (t & 1) * 256, r0 = (t >> 1) * 128;
    const _Float16* Pp = P + (size_t)bz * 2048 * 2048;
    const _Float16* Bp = (isO2 ? Xt : Vt) + (size_t)bz * 512 * 2048;
    float* Op = (isO2 ? O2 : O1) + (size_t)bz * 2048 * 512;

    floatx4 acc[4][8];
#pragma unroll
    for (int i = 0; i < 4; i++)
#pragma unroll
        for (int j = 0; j < 8; j++) acc[i][j] = (floatx4){0.f, 0.f, 0.f, 0.f};

    if (!isO2) {
        for (int k0 = 0; k0 < 2048; k0 += 64) {
            stage64<128>(Pp + (size_t)r0 * 2048 + k0, 2048, lds, tid);
            stage64<256>(Bp + (size_t)c0 * 2048 + k0, 2048, lds + 8192, tid);
            __syncthreads();
#pragma unroll
            for (int ks = 0; ks < 2; ks++) {
                f16x8 a[4], b[8];
#pragma unroll
                for (int i = 0; i < 4; i++)
                    a[i] = ldfrag64(lds, wM + i * 16 + lrow, ks * 4 + kq);
#pragma unroll
                for (int i = 0; i < 8; i++)
                    b[i] = ldfrag64(lds + 8192, wN + i * 16 + lrow, ks * 4 + kq);
#pragma unroll
                for (int mi = 0; mi < 4; mi++)
#pragma unroll
                    for (int ni = 0; ni < 8; ni++)
                        acc[mi][ni] = mfma16(a[mi], b[ni], acc[mi][ni]);
            }
            __syncthreads();   // compute done before next restage (WAR)
        }
    } else {
        _Float16* As_ = lds;                // 128 x 64, transposed P
        const int mPair = (tid & 63) * 2;   // m pair within 128-tile
        const int kBase = (tid >> 6) * 16;  // 16 k's per thread

        unsigned u[16];
        loadtr16(Pp, r0, mPair, kBase, 0, u);
        for (int k0 = 0; k0 < 2048; k0 += 64) {
            // transpose P[k][m] -> As[m][k]; (row>>1)&7 swizzle: rows are even,
            // so this covers all 8 oct groups (all 32 banks) per wave-write.
            const int sw = (mPair >> 1) & 7;
#pragma unroll
            for (int half = 0; half < 2; half++) {
                const int oct = (kBase >> 3) + half;
                F8 w0, w1;
#pragma unroll
                for (int j = 0; j < 8; j++) {
                    const unsigned g = u[half * 8 + j];
                    w0.u[j] = (unsigned short)(g & 0xffffu);
                    w1.u[j] = (unsigned short)(g >> 16);
                }
                *(f16x8*)&As_[mPair * 64 + ((oct ^ sw) << 3)] = w0.v;
                *(f16x8*)&As_[(mPair + 1) * 64 + ((oct ^ sw) << 3)] = w1.v;
            }
            stage64<256>(Bp + (size_t)c0 * 2048 + k0, 2048, lds + 8192, tid);
            __syncthreads();   // drains B gld16; As ds_writes visible
            if (k0 < 2048 - 64)
                loadtr16(Pp, r0, mPair, kBase, k0 + 64, u);   // fly under MFMA
#pragma unroll
            for (int ks = 0; ks < 2; ks++) {
                f16x8 a[4], b[8];
#pragma unroll
                for (int i = 0; i < 4; i++)
                    a[i] = ldfragA(As_, wM + i * 16 + lrow, ks * 4 + kq);
#pragma unroll
                for (int i = 0; i < 8; i++)
                    b[i] = ldfrag64(lds + 8192, wN + i * 16 + lrow, ks * 4 + kq);
#pragma unroll
                for (int mi = 0; mi < 4; mi++)
#pragma unroll
                    for (int ni = 0; ni < 8; ni++)
                        acc[mi][ni] = mfma16(a[mi], b[ni], acc[mi][ni]);
            }
            __syncthreads();   // WAR: next iter rewrites As/Bs
        }
    }
#pragma unroll
    for (int mi = 0; mi < 4; mi++)
#pragma unroll
        for (int ni = 0; ni < 8; ni++) {
            const int row = r0 + wM + mi * 16 + kq * 4;
            const int col = c0 + wN + ni * 16 + lrow;
            float* dst = Op + (size_t)row * 512 + col;
#pragma unroll
            for (int r = 0; r < 4; r++) dst[(size_t)r * 512] = acc[mi][ni][r];
        }
}

extern "C" void kernel_launch(void* const* d_in, const int* in_sizes, int n_in,
                              void* d_out, int out_size, void* d_ws, size_t ws_size,
                              hipStream_t stream)
{
    (void)in_sizes; (void)n_in; (void)out_size; (void)ws_size;
    const float* in1 = (const float*)d_in[0];
    const float* in2 = (const float*)d_in[1];
    const float* Ww  = (const float*)d_in[2];
    const float* Wb  = (const float*)d_in[3];
    float* out = (float*)d_out;

    char* ws = (char*)d_ws;
    _Float16* S   = (_Float16*)ws;                       // 64 MiB (fp16, full batch)
    _Float16* P   = (_Float16*)(ws + 67108864ull);       // 64 MiB
    _Float16* q16 = (_Float16*)(ws + 134217728ull);      // 16 MiB
    _Float16* x16 = (_Float16*)(ws + 150994944ull);      // 16 MiB
    _Float16* k16 = (_Float16*)(ws + 167772160ull);      // 16 MiB
    _Float16* vt  = (_Float16*)(ws + 184549376ull);      // 16 MiB
    _Float16* xt  = (_Float16*)(ws + 201326592ull);      // 16 MiB
    _Float16* w16 = (_Float16*)(ws + 218103808ull);      // 0.5 MiB

    k_prep2<<<dim3(8, 32, 17), 256, 0, stream>>>(in1, in2, x16, xt, k16, vt, Ww, w16);
    k_qgemm16<<<512, 256, 0, stream>>>(x16, w16, Wb, q16);
    k_scores16<<<1024, 256, 0, stream>>>(q16, k16, S);
    k_softmax<<<4096, 256, 0, stream>>>(S, P);
    k_out12<<<512, 256, 0, stream>>>(P, vt, xt, out, out + 8388608);
}